// Round 10
// baseline (204.301 us; speedup 1.0000x reference)
//
#include <hip/hip_runtime.h>
#include <hip/hip_bf16.h>

typedef __bf16 bf16x8 __attribute__((ext_vector_type(8)));
typedef float  f32x4  __attribute__((ext_vector_type(4)));
typedef float  f32x16 __attribute__((ext_vector_type(16)));

#define SEQ  4096
#define NH   16
#define HD   128
#define QBLK 128
#define KVBLK 64
#define NT   (SEQ / KVBLK)     // 64 kv tiles
#define STR  (NH * HD)
#define TILE_E 8192            // elems per bf16 tile image (64*128)
#define WS_ELEMS ((size_t)NH * NT * TILE_E)
#define THR  11.0f             // defer-max threshold (exp2 domain)

__device__ __forceinline__ bf16x8 cvt_bf16x8(f32x4 a, f32x4 b, float scale) {
    bf16x8 v;
    v[0] = (__bf16)(a[0]*scale); v[1] = (__bf16)(a[1]*scale);
    v[2] = (__bf16)(a[2]*scale); v[3] = (__bf16)(a[3]*scale);
    v[4] = (__bf16)(b[0]*scale); v[5] = (__bf16)(b[1]*scale);
    v[6] = (__bf16)(b[2]*scale); v[7] = (__bf16)(b[3]*scale);
    return v;
}

__device__ __forceinline__ int vswz(int d) { return ((d & 7) ^ ((d >> 3) & 7)) << 3; }

// ============ prep: K image [key][d] row-swizzled; V image [d][p], p = key with bits2<->3 swapped ============
__global__ __launch_bounds__(256) void prep_kernel(
    const float* __restrict__ K, const float* __restrict__ V, __bf16* __restrict__ ws)
{
    const int tid = threadIdx.x;
    const int bid = blockIdx.x;
    const int h   = bid >> 6;
    const int t   = bid & 63;

    __bf16* kimg = ws + (size_t)(h*NT + t) * TILE_E;
    __bf16* vimg = ws + WS_ELEMS + (size_t)(h*NT + t) * TILE_E;

    // K image (unchanged from R9): e = (row*128 + ch*8) ^ ((row&7)<<3)
    const int krb = tid >> 4, kch = tid & 15;
    #pragma unroll
    for (int it = 0; it < 4; ++it) {
        const int row = it*16 + krb;
        const float* src = K + (size_t)(t*KVBLK + row)*STR + h*HD + kch*8;
        f32x4 a = *(const f32x4*)src;
        f32x4 b = *(const f32x4*)(src + 4);
        const int e = (row*HD + kch*8) ^ ((row & 7) << 3);
        *(bf16x8*)&kimg[e] = cvt_bf16x8(a, b, 1.0f);
    }

    // V image: vimg[d][p] = V[sigma(p)][d], sigma = swap bits 2,3. Thread owns
    // p-run 8m..8m+7 at 4 d-cols; keys KB+8*(j>>2)+(j&3).
    const int m  = tid >> 5;          // 0..7
    const int dg = tid & 31;          // 0..31
    const int vd = 4 * dg;
    const int KB = 32*(m>>2) + 16*((m>>1)&1) + 4*(m&1);
    bf16x8 vt[4];
    #pragma unroll
    for (int j = 0; j < 8; ++j) {
        const int kr = t*KVBLK + KB + 8*(j>>2) + (j&3);
        f32x4 va = *(const f32x4*)(V + (size_t)kr*STR + h*HD + vd);
        vt[0][j] = (__bf16)va[0]; vt[1][j] = (__bf16)va[1];
        vt[2][j] = (__bf16)va[2]; vt[3][j] = (__bf16)va[3];
    }
    #pragma unroll
    for (int i = 0; i < 4; ++i) {
        const int d = vd + i;
        const int e = (d*KVBLK + 8*m) ^ vswz(d);
        *(bf16x8*)&vimg[e] = vt[i];
    }
}

// ============ main: 32x32 MFMA, 32 q per wave, QBLK=128, gload_lds dbuf ============
__global__ __launch_bounds__(256) void fattn3_kernel(
    const float* __restrict__ Q, const __bf16* __restrict__ ws, float* __restrict__ O)
{
    __shared__ __align__(16) __bf16 lds[2][16384];   // [buf][K 8192 | V 8192] = 64 KB

    const int tid  = threadIdx.x;
    const int lane = tid & 63;
    const int wv   = tid >> 6;
    const int l31  = lane & 31;   // q (in S^T cols / O d-col) index
    const int hi   = lane >> 5;   // half-select

    const int bid = blockIdx.x;
    const int h   = bid & (NH - 1);
    const int qt  = bid >> 4;                      // 0..31
    const int qb  = (qt < 16) ? (31 - qt) : (qt - 16);  // CU pair {qt,qt+16} -> 66 steps
    const int q0  = qb * QBLK;
    const int qlo_w = q0 + 32*wv;                  // this wave's 32 q rows
    const int qg    = qlo_w + l31;                 // this lane's q

    const float scale = 0.08838834764831845f * 1.4426950408889634f; // /sqrt(128)*log2e

    // ---- Q fragments (B operand): lane holds Q[qg][16ks+8hi .. +7], ks=0..7 ----
    bf16x8 qf[8];
    {
        const float* qrow = Q + (size_t)qg * STR + h*HD;
        #pragma unroll
        for (int ks = 0; ks < 8; ++ks) {
            const int d0 = 16*ks + 8*hi;
            qf[ks] = cvt_bf16x8(*(const f32x4*)(qrow + d0), *(const f32x4*)(qrow + d0 + 4), scale);
        }
    }

    // O accumulator: oacc[dt][reg] = O[q = qlo_w + (reg&3)+8*(reg>>2)+4hi][d = 32dt + l31]
    f32x16 oacc[4];
    #pragma unroll
    for (int i = 0; i < 4; ++i)
        #pragma unroll
        for (int r = 0; r < 16; ++r) oacc[i][r] = 0.f;
    float mrow = -1e30f, lrow = 0.f;

    const __bf16* kws = ws;
    const __bf16* vws = ws + WS_ELEMS;
    char* ldsbase = (char*)&lds[0][0];

    #define ISSUE(TT, BUF)                                                          \
    {                                                                               \
        const size_t tb = (size_t)(h*NT + (TT)) * TILE_E;                           \
        _Pragma("unroll")                                                           \
        for (int ci = 0; ci < 4; ++ci) {                                            \
            const int ch = wv*4 + ci;                                               \
            const __bf16* gk = kws + tb + ch*512 + lane*8;                          \
            const __bf16* gv = vws + tb + ch*512 + lane*8;                          \
            __builtin_amdgcn_global_load_lds(                                       \
                (const __attribute__((address_space(1))) void*)gk,                  \
                (__attribute__((address_space(3))) void*)(ldsbase + (BUF)*32768 + ch*1024),          \
                16, 0, 0);                                                          \
            __builtin_amdgcn_global_load_lds(                                       \
                (const __attribute__((address_space(1))) void*)gv,                  \
                (__attribute__((address_space(3))) void*)(ldsbase + (BUF)*32768 + 16384 + ch*1024),  \
                16, 0, 0);                                                          \
        }                                                                           \
    }

    const int nkv = 2*qb + 2;
    ISSUE(0, 0);
    int buf = 0;

    for (int kb = 0; kb < nkv; ++kb) {
        const int k0 = kb * KVBLK;

        __syncthreads();   // drains vmcnt -> tile kb resident; joins waves
        if (kb + 1 < nkv) ISSUE(kb + 1, buf ^ 1);

        if (k0 <= qlo_w + 31) {   // else: tile fully masked for this wave
            const __bf16* bK = &lds[buf][0];
            const __bf16* bV = &lds[buf][8192];

            // ---- swapped QK^T (32x32x16): s_kt[reg] = S^T[k0+32kt+(reg&3)+8(reg>>2)+4hi][qg]
            f32x16 s0, s1;
            #pragma unroll
            for (int r = 0; r < 16; ++r) { s0[r] = 0.f; s1[r] = 0.f; }
            __builtin_amdgcn_s_setprio(1);
            #pragma unroll
            for (int ks = 0; ks < 8; ++ks) {
                const int e0 = (l31*HD + 16*ks + 8*hi) ^ ((l31 & 7) << 3);
                bf16x8 ak = *(const bf16x8*)&bK[e0];
                s0 = __builtin_amdgcn_mfma_f32_32x32x16_bf16(ak, qf[ks], s0, 0, 0, 0);
            }
            #pragma unroll
            for (int ks = 0; ks < 8; ++ks) {
                const int e1 = ((32 + l31)*HD + 16*ks + 8*hi) ^ ((l31 & 7) << 3);
                bf16x8 ak = *(const bf16x8*)&bK[e1];
                s1 = __builtin_amdgcn_mfma_f32_32x32x16_bf16(ak, qf[ks], s1, 0, 0, 0);
            }
            __builtin_amdgcn_s_setprio(0);

            // ---- causal mask (band only) ----
            if (k0 + 63 > qlo_w) {
                #pragma unroll
                for (int reg = 0; reg < 16; ++reg) {
                    const int key0 = k0 + (reg & 3) + 8*(reg >> 2) + 4*hi;
                    if (key0 > qg)      s0[reg] = -1e30f;
                    if (key0 + 32 > qg) s1[reg] = -1e30f;
                }
            }

            // ---- online softmax (exp2 domain, defer-max); q lane-local, 1 cross shuffle ----
            float pmax = -1e30f;
            #pragma unroll
            for (int reg = 0; reg < 16; ++reg)
                pmax = fmaxf(pmax, fmaxf(s0[reg], s1[reg]));
            pmax = fmaxf(pmax, __shfl_xor(pmax, 32, 64));
            if (!__all(pmax - mrow <= THR)) {
                const float mn = fmaxf(mrow, pmax);
                const float alpha = exp2f(mrow - mn);
                mrow = mn;
                #pragma unroll
                for (int reg = 0; reg < 16; ++reg) {
                    const float aq = __shfl(alpha, (reg & 3) + 8*(reg >> 2) + 4*hi, 64);
                    #pragma unroll
                    for (int dt = 0; dt < 4; ++dt) oacc[dt][reg] *= aq;
                }
                lrow *= alpha;
            }
            float rs = 0.f;
            #pragma unroll
            for (int reg = 0; reg < 16; ++reg) {
                s0[reg] = exp2f(s0[reg] - mrow); rs += s0[reg];
                s1[reg] = exp2f(s1[reg] - mrow); rs += s1[reg];
            }
            rs += __shfl_xor(rs, 32, 64);
            lrow += rs;

            // ---- P -> A fragments: consecutive-register repack (sigma absorbed into V image) ----
            bf16x8 pa[4];
            #pragma unroll
            for (int j = 0; j < 8; ++j) {
                pa[0][j] = (__bf16)s0[j];     pa[1][j] = (__bf16)s0[8 + j];
                pa[2][j] = (__bf16)s1[j];     pa[3][j] = (__bf16)s1[8 + j];
            }

            // ---- PV (32x32x16): oacc[dt] += P * V^T ----
            __builtin_amdgcn_s_setprio(1);
            #pragma unroll
            for (int dt = 0; dt < 4; ++dt) {
                const int d = 32*dt + l31;
                const int sz = vswz(d);
                #pragma unroll
                for (int ks = 0; ks < 4; ++ks) {
                    const int e = (d*KVBLK + 16*ks + 8*hi) ^ sz;
                    bf16x8 bv = *(const bf16x8*)&bV[e];
                    oacc[dt] = __builtin_amdgcn_mfma_f32_32x32x16_bf16(pa[ks], bv, oacc[dt], 0, 0, 0);
                }
            }
            __builtin_amdgcn_s_setprio(0);
        }

        buf ^= 1;
    }

    // ---- epilogue ----
    {
        const float linv = 1.0f / lrow;
        #pragma unroll
        for (int reg = 0; reg < 16; ++reg) {
            const int row = (reg & 3) + 8*(reg >> 2) + 4*hi;
            const float lq = __shfl(linv, row, 64);
            float* obase = O + (size_t)(qlo_w + row)*STR + h*HD + l31;
            #pragma unroll
            for (int dt = 0; dt < 4; ++dt)
                obase[32*dt] = oacc[dt][reg] * lq;
        }
    }
    #undef ISSUE
}

extern "C" void kernel_launch(void* const* d_in, const int* in_sizes, int n_in,
                              void* d_out, int out_size, void* d_ws, size_t ws_size,
                              hipStream_t stream) {
    const float* Q = (const float*)d_in[0];
    const float* K = (const float*)d_in[1];
    const float* V = (const float*)d_in[2];
    float* O = (float*)d_out;

    prep_kernel<<<dim3(NH * NT), dim3(256), 0, stream>>>(K, V, (__bf16*)d_ws);
    fattn3_kernel<<<dim3((SEQ / QBLK) * NH), dim3(256), 0, stream>>>(Q, (const __bf16*)d_ws, O);
}

// Round 12
// 146.987 us; speedup vs baseline: 1.3899x; 1.3899x over previous
//
#include <hip/hip_runtime.h>
#include <hip/hip_bf16.h>

typedef __bf16 bf16x8 __attribute__((ext_vector_type(8)));
typedef __bf16 bf16x4 __attribute__((ext_vector_type(4)));
typedef float  f32x4  __attribute__((ext_vector_type(4)));

#define SEQ   4096
#define NH    16
#define HD    128
#define KVB   32                 // kv tile = 32 keys
#define NT32  128                // tiles per head
#define STR   (NH * HD)
#define TE    4096               // elems per tile image (32*128)
#define WSK   ((size_t)NH * NT32 * TE)
#define THRD  11.0f
#define MASKV -3.0e38f

__device__ __forceinline__ bf16x8 cvt_bf16x8(f32x4 a, f32x4 b, float s) {
    bf16x8 v;
    v[0] = (__bf16)(a[0]*s); v[1] = (__bf16)(a[1]*s);
    v[2] = (__bf16)(a[2]*s); v[3] = (__bf16)(a[3]*s);
    v[4] = (__bf16)(b[0]*s); v[5] = (__bf16)(b[1]*s);
    v[6] = (__bf16)(b[2]*s); v[7] = (__bf16)(b[3]*s);
    return v;
}

// ============ prep: per-32-key-tile images ============
// K image: kimg[e], e = (row*128 + col) ^ ((row&7)<<3)
// V image: vimg[d][p] = V[key(p)][d], key(p) = (p&3) | (((p>>3)&3)<<2) | (((p>>2)&1)<<4)
//          stored at e = d*32 + 8*((p>>3) ^ ((d>>1)&3)) + (p&7)
__global__ __launch_bounds__(256) void prep_kernel(
    const float* __restrict__ K, const float* __restrict__ V, __bf16* __restrict__ ws)
{
    const int tid = threadIdx.x;
    const int bid = blockIdx.x;
    const int h   = bid >> 7;
    const int t   = bid & 127;

    __bf16* kimg = ws + (size_t)(h*NT32 + t) * TE;
    __bf16* vimg = ws + WSK + (size_t)(h*NT32 + t) * TE;

    // K part: row = tid>>3 (0..31), chunks ch = (tid&7)*2 + {0,1}
    const int row = tid >> 3;
    #pragma unroll
    for (int u = 0; u < 2; ++u) {
        const int ch = (tid & 7)*2 + u;
        const float* src = K + (size_t)(t*KVB + row)*STR + h*HD + ch*8;
        f32x4 a = *(const f32x4*)src;
        f32x4 b = *(const f32x4*)(src + 4);
        const int e = (row*HD + ch*8) ^ ((row & 7) << 3);
        *(bf16x8*)&kimg[e] = cvt_bf16x8(a, b, 1.0f);
    }

    // V part: thread -> (4 d-cols, pl, ihalf); keys 16*ih + 4*pl + r
    const int d4 = (tid & 31) * 4;
    const int pl = (tid >> 5) & 3;
    const int ih = tid >> 7;
    f32x4 va[4];
    #pragma unroll
    for (int r = 0; r < 4; ++r) {
        const int kr = t*KVB + 16*ih + 4*pl + r;
        va[r] = *(const f32x4*)(V + (size_t)kr*STR + h*HD + d4);
    }
    #pragma unroll
    for (int i4 = 0; i4 < 4; ++i4) {
        const int d = d4 + i4;
        bf16x4 w;
        w[0] = (__bf16)va[0][i4]; w[1] = (__bf16)va[1][i4];
        w[2] = (__bf16)va[2][i4]; w[3] = (__bf16)va[3][i4];
        const int e = d*KVB + 8*(pl ^ ((d >> 1) & 3)) + 4*ih;
        *(bf16x4*)&vimg[e] = w;
    }
}

// ============ main: 8 waves, intra-block kv-split (2 groups), q-pair phases ============
__global__ __launch_bounds__(512, 4) void fattn4_kernel(
    const float* __restrict__ Q, const __bf16* __restrict__ ws, float* __restrict__ O)
{
    // [grp][buf][K 8KB | V 8KB] staging = 64 KB, + 512 B m/l exchange
    __shared__ __align__(16) char ldsraw[66048];

    const int tid  = threadIdx.x;
    const int lane = tid & 63;
    const int wv   = tid >> 6;       // 0..7
    const int grp  = wv >> 2;        // 0 = lower kv half, 1 = upper
    const int wg   = wv & 3;         // q sub-tile within block
    const int c    = lane & 15;
    const int g    = lane >> 4;

    const int bid = blockIdx.x;
    const int h   = bid & 15;
    const int j   = bid >> 4;        // 0..31; phases handle qb = 63-j then j

    const __bf16* kws = ws;
    const __bf16* vws = ws + WSK;
    float* ml = (float*)(ldsraw + 65536);

    #define ISSUE(TT, BUF)  do {                                                       \
        const size_t tb_ = (size_t)(h*NT32 + (TT)) * TE;                               \
        _Pragma("unroll")                                                              \
        for (int ci = 0; ci < 4; ++ci) {                                               \
            const int fb = (4*wg + ci) * 1024;                                         \
            const __bf16* src = (fb < 8192) ? (kws + tb_ + (fb >> 1) + lane*8)         \
                                            : (vws + tb_ + ((fb - 8192) >> 1) + lane*8); \
            __builtin_amdgcn_global_load_lds(                                          \
                (const __attribute__((address_space(1))) void*)src,                    \
                (__attribute__((address_space(3))) void*)(ldsraw + grp*32768 + (BUF)*16384 + fb), \
                16, 0, 0);                                                             \
        }                                                                              \
    } while (0)

    int buf = 0;
    ISSUE(grp * (63 - j + 1), 0);    // phase-0 tile 0 for this group

    for (int ph = 0; ph < 2; ++ph) {
        const int qb  = ph ? j : (63 - j);
        const int q0  = qb * 64;
        const int qlo = q0 + 16*wg;
        const int qg  = qlo + c;
        const int nst = qb + 1;          // steps for this phase (per group)
        const int tb0 = grp * nst;       // group's kv-tile base

        const float scale = 0.08838834764831845f * 1.4426950408889634f; // /sqrt(128)*log2e
        bf16x8 qf[4];
        {
            const float* qrow = Q + (size_t)qg * STR + h*HD;
            #pragma unroll
            for (int ks = 0; ks < 4; ++ks) {
                const int d0 = 32*ks + 8*g;
                qf[ks] = cvt_bf16x8(*(const f32x4*)(qrow + d0), *(const f32x4*)(qrow + d0 + 4), scale);
            }
        }

        f32x4 oacc[8];
        #pragma unroll
        for (int i = 0; i < 8; ++i) { oacc[i][0]=0.f; oacc[i][1]=0.f; oacc[i][2]=0.f; oacc[i][3]=0.f; }
        float mrow = -1e30f, lrow = 0.f;

        for (int t = 0; t < nst; ++t) {
            __syncthreads();             // joins waves + drains vmcnt: tile t resident
            if (t + 1 < nst)  ISSUE(tb0 + t + 1, buf ^ 1);
            else if (ph == 0) ISSUE(grp * (j + 1), buf ^ 1);   // prefetch phase-1 tile 0

            const int k0 = (tb0 + t) * KVB;
            if (k0 <= qlo + 15) {        // else: fully masked for this wave's q rows
                const __bf16* bK = (const __bf16*)(ldsraw + grp*32768 + buf*16384);
                const __bf16* bV = bK + 4096;   // V image at byte 8192 = elem 4096 (R11 bug: was +8192)

                // ---- swapped QK^T (two 16-key subtiles) ----
                f32x4 s0 = {0.f,0.f,0.f,0.f}, s1 = {0.f,0.f,0.f,0.f};
                __builtin_amdgcn_s_setprio(1);
                #pragma unroll
                for (int ks = 0; ks < 4; ++ks) {
                    const int e0 = (c*HD + 32*ks + 8*g) ^ ((c & 7) << 3);
                    bf16x8 ak0 = *(const bf16x8*)&bK[e0];
                    bf16x8 ak1 = *(const bf16x8*)&bK[e0 + 16*HD];
                    s0 = __builtin_amdgcn_mfma_f32_16x16x32_bf16(ak0, qf[ks], s0, 0, 0, 0);
                    s1 = __builtin_amdgcn_mfma_f32_16x16x32_bf16(ak1, qf[ks], s1, 0, 0, 0);
                }
                __builtin_amdgcn_s_setprio(0);

                // ---- causal mask (MASKV so exp2(s - mrow) underflows to 0) ----
                if (k0 + 31 > qlo) {
                    #pragma unroll
                    for (int r = 0; r < 4; ++r) {
                        if (k0 + 4*g + r > qg)      s0[r] = MASKV;
                        if (k0 + 16 + 4*g + r > qg) s1[r] = MASKV;
                    }
                }

                // ---- online softmax (exp2 domain, defer-max) ----
                float pmax = fmaxf(fmaxf(fmaxf(s0[0],s0[1]), fmaxf(s0[2],s0[3])),
                                   fmaxf(fmaxf(s1[0],s1[1]), fmaxf(s1[2],s1[3])));
                pmax = fmaxf(pmax, __shfl_xor(pmax, 16, 64));
                pmax = fmaxf(pmax, __shfl_xor(pmax, 32, 64));
                if (!__all(pmax - mrow <= THRD)) {
                    const float mn = fmaxf(mrow, pmax);
                    const float alpha = exp2f(mrow - mn);
                    mrow = mn;
                    f32x4 aq;
                    #pragma unroll
                    for (int r = 0; r < 4; ++r) aq[r] = __shfl(alpha, 20*g + r, 64);
                    #pragma unroll
                    for (int dt = 0; dt < 8; ++dt) oacc[dt] *= aq;
                    lrow *= alpha;
                }
                float rs = 0.f;
                #pragma unroll
                for (int r = 0; r < 4; ++r) {
                    s0[r] = exp2f(s0[r] - mrow); rs += s0[r];
                    s1[r] = exp2f(s1[r] - mrow); rs += s1[r];
                }
                rs += __shfl_xor(rs, 16, 64);
                rs += __shfl_xor(rs, 32, 64);
                lrow += rs;

                // ---- P -> single A-fragment (K=32), sigma absorbed into V image ----
                bf16x8 pa;
                pa[0]=(__bf16)s0[0]; pa[1]=(__bf16)s0[1]; pa[2]=(__bf16)s0[2]; pa[3]=(__bf16)s0[3];
                pa[4]=(__bf16)s1[0]; pa[5]=(__bf16)s1[1]; pa[6]=(__bf16)s1[2]; pa[7]=(__bf16)s1[3];

                // ---- PV ----
                __builtin_amdgcn_s_setprio(1);
                #pragma unroll
                for (int dt = 0; dt < 8; ++dt) {
                    const int d = 16*dt + c;
                    const int e = d*KVB + ((8*g) ^ (((d >> 1) & 3) << 3));
                    bf16x8 bv = *(const bf16x8*)&bV[e];
                    oacc[dt] = __builtin_amdgcn_mfma_f32_16x16x32_bf16(pa, bv, oacc[dt], 0, 0, 0);
                }
                __builtin_amdgcn_s_setprio(0);
            }
            buf ^= 1;
        }

        // ---- merge the two kv-halves; group 0 writes O ----
        __syncthreads();                 // all compute done
        const int dumpbuf = buf ^ 1;     // buf holds in-flight next-phase tile0; other is free
        if (grp == 1) {
            if (lane < 16) { ml[wg*32 + c] = mrow; ml[wg*32 + 16 + c] = lrow; }
            float* df = (float*)(ldsraw + (wg >> 1)*32768 + dumpbuf*16384 + (wg & 1)*8192);
            #pragma unroll
            for (int dt = 0; dt < 8; ++dt)
                #pragma unroll
                for (int r = 0; r < 4; ++r)
                    df[(4*g + r)*128 + 16*dt + c] = oacc[dt][r];
        }
        __syncthreads();
        if (grp == 0) {
            const float mB = ml[wg*32 + c];
            const float lB = ml[wg*32 + 16 + c];
            const float mq = fmaxf(mrow, mB);
            const float sA = exp2f(mrow - mq);
            const float sB = exp2f(mB - mq);
            const float inv = 1.0f / (lrow*sA + lB*sB);
            const float cA0 = sA * inv, cB0 = sB * inv;
            const float* df = (const float*)(ldsraw + (wg >> 1)*32768 + dumpbuf*16384 + (wg & 1)*8192);
            #pragma unroll
            for (int r = 0; r < 4; ++r) {
                const float cA = __shfl(cA0, 20*g + r, 64);
                const float cB = __shfl(cB0, 20*g + r, 64);
                float* orow = O + (size_t)(qlo + 4*g + r)*STR + h*HD;
                #pragma unroll
                for (int dt = 0; dt < 8; ++dt)
                    orow[16*dt + c] = oacc[dt][r]*cA + df[(4*g + r)*128 + 16*dt + c]*cB;
            }
        }
        // next phase's loop-top __syncthreads() protects the dump region before reuse
    }
    #undef ISSUE
}

extern "C" void kernel_launch(void* const* d_in, const int* in_sizes, int n_in,
                              void* d_out, int out_size, void* d_ws, size_t ws_size,
                              hipStream_t stream) {
    const float* Q = (const float*)d_in[0];
    const float* K = (const float*)d_in[1];
    const float* V = (const float*)d_in[2];
    float* O = (float*)d_out;

    prep_kernel<<<dim3(NH * NT32), dim3(256), 0, stream>>>(K, V, (__bf16*)d_ws);
    fattn4_kernel<<<dim3(32 * NH), dim3(512), 0, stream>>>(Q, (const __bf16*)d_ws, O);
}

// Round 14
// 145.487 us; speedup vs baseline: 1.4043x; 1.0103x over previous
//
#include <hip/hip_runtime.h>
#include <hip/hip_bf16.h>

typedef __bf16 bf16x8 __attribute__((ext_vector_type(8)));
typedef __bf16 bf16x4 __attribute__((ext_vector_type(4)));
typedef float  f32x4  __attribute__((ext_vector_type(4)));

#define SEQ   4096
#define NH    16
#define HD    128
#define KVB   32                 // kv tile = 32 keys
#define NT32  128                // tiles per head
#define STR   (NH * HD)
#define TE    4096               // elems per tile image (32*128)
#define WSK   ((size_t)NH * NT32 * TE)
#define THRD  11.0f
#define MASKV -3.0e38f

__device__ __forceinline__ bf16x8 cvt_bf16x8(f32x4 a, f32x4 b, float s) {
    bf16x8 v;
    v[0] = (__bf16)(a[0]*s); v[1] = (__bf16)(a[1]*s);
    v[2] = (__bf16)(a[2]*s); v[3] = (__bf16)(a[3]*s);
    v[4] = (__bf16)(b[0]*s); v[5] = (__bf16)(b[1]*s);
    v[6] = (__bf16)(b[2]*s); v[7] = (__bf16)(b[7-7]*0.0f + b[3]*s);
    return v;
}

// ============ prep: per-32-key-tile images (unchanged from R12) ============
__global__ __launch_bounds__(256) void prep_kernel(
    const float* __restrict__ K, const float* __restrict__ V, __bf16* __restrict__ ws)
{
    const int tid = threadIdx.x;
    const int bid = blockIdx.x;
    const int h   = bid >> 7;
    const int t   = bid & 127;

    __bf16* kimg = ws + (size_t)(h*NT32 + t) * TE;
    __bf16* vimg = ws + WSK + (size_t)(h*NT32 + t) * TE;

    const int row = tid >> 3;
    #pragma unroll
    for (int u = 0; u < 2; ++u) {
        const int ch = (tid & 7)*2 + u;
        const float* src = K + (size_t)(t*KVB + row)*STR + h*HD + ch*8;
        f32x4 a = *(const f32x4*)src;
        f32x4 b = *(const f32x4*)(src + 4);
        const int e = (row*HD + ch*8) ^ ((row & 7) << 3);
        *(bf16x8*)&kimg[e] = cvt_bf16x8(a, b, 1.0f);
    }

    const int d4 = (tid & 31) * 4;
    const int pl = (tid >> 5) & 3;
    const int ih = tid >> 7;
    f32x4 va[4];
    #pragma unroll
    for (int r = 0; r < 4; ++r) {
        const int kr = t*KVB + 16*ih + 4*pl + r;
        va[r] = *(const f32x4*)(V + (size_t)kr*STR + h*HD + d4);
    }
    #pragma unroll
    for (int i4 = 0; i4 < 4; ++i4) {
        const int d = d4 + i4;
        bf16x4 w;
        w[0] = (__bf16)va[0][i4]; w[1] = (__bf16)va[1][i4];
        w[2] = (__bf16)va[2][i4]; w[3] = (__bf16)va[3][i4];
        const int e = d*KVB + 8*(pl ^ ((d >> 1) & 3)) + 4*ih;
        *(bf16x4*)&vimg[e] = w;
    }
}

// ============ main: 8 waves, kv-split x2, 32 q per wave (2 subtiles), QBLK=128 ============
__global__ __launch_bounds__(512) void fattn5_kernel(
    const float* __restrict__ Q, const __bf16* __restrict__ ws, float* __restrict__ O)
{
    // staging: [grp][buf] 16KB each = 64 KB (doubles as fp32 [128][128] merge dump)
    __shared__ __align__(16) char ldsraw[66560];

    const int tid  = threadIdx.x;
    const int lane = tid & 63;
    const int wv   = tid >> 6;       // 0..7
    const int grp  = wv >> 2;        // 0 = lower kv half, 1 = upper
    const int wg   = wv & 3;         // q wave within block (32 q each)
    const int c    = lane & 15;
    const int g    = lane >> 4;

    const int bid = blockIdx.x;
    const int h   = bid & 15;
    const int j   = bid >> 4;        // 0..15; phases: qb = 31-j, then j

    const __bf16* kws = ws;
    const __bf16* vws = ws + WSK;
    float* ml = (float*)(ldsraw + 65536);   // m at [0,128), l at [128,256)

    #define ISSUE(TT, BUF)  do {                                                       \
        const size_t tb_ = (size_t)(h*NT32 + (TT)) * TE;                               \
        _Pragma("unroll")                                                              \
        for (int ci = 0; ci < 4; ++ci) {                                               \
            const int fb = (4*wg + ci) * 1024;                                         \
            const __bf16* src = (fb < 8192) ? (kws + tb_ + (fb >> 1) + lane*8)         \
                                            : (vws + tb_ + ((fb - 8192) >> 1) + lane*8); \
            __builtin_amdgcn_global_load_lds(                                          \
                (const __attribute__((address_space(1))) void*)src,                    \
                (__attribute__((address_space(3))) void*)(ldsraw + grp*32768 + (BUF)*16384 + fb), \
                16, 0, 0);                                                             \
        }                                                                              \
    } while (0)

    const float scale = 0.08838834764831845f * 1.4426950408889634f; // /sqrt(128)*log2e

    for (int ph = 0; ph < 2; ++ph) {
        const int qb  = ph ? j : (31 - j);
        const int q0  = qb * 128;
        const int qlo0 = q0 + 32*wg;       // subtile 0 base; subtile 1 = +16
        const int nst = 2*qb + 2;          // steps per group this phase
        const int tb0 = grp * nst;

        // ---- Q fragments for both subtiles ----
        bf16x8 qf[2][4];
        #pragma unroll
        for (int sub = 0; sub < 2; ++sub) {
            const float* qrow = Q + (size_t)(qlo0 + 16*sub + c) * STR + h*HD;
            #pragma unroll
            for (int ks = 0; ks < 4; ++ks) {
                const int d0 = 32*ks + 8*g;
                qf[sub][ks] = cvt_bf16x8(*(const f32x4*)(qrow + d0), *(const f32x4*)(qrow + d0 + 4), scale);
            }
        }

        f32x4 oacc[2][8];
        #pragma unroll
        for (int s2 = 0; s2 < 2; ++s2)
            #pragma unroll
            for (int i = 0; i < 8; ++i) { oacc[s2][i][0]=0.f; oacc[s2][i][1]=0.f; oacc[s2][i][2]=0.f; oacc[s2][i][3]=0.f; }
        float mrow[2] = {-1e30f, -1e30f};
        float lrow[2] = {0.f, 0.f};

        int buf = 0;
        ISSUE(tb0, 0);

        for (int t = 0; t < nst; ++t) {
            __syncthreads();             // joins waves + drains vmcnt: tile resident
            if (t + 1 < nst) ISSUE(tb0 + t + 1, buf ^ 1);

            const int k0 = (tb0 + t) * KVB;
            if (k0 <= qlo0 + 47) {       // at least one subtile attends this tile
                const __bf16* bK = (const __bf16*)(ldsraw + grp*32768 + buf*16384);
                const __bf16* bV = bK + 4096;

                // ---- swapped QK^T: 4 reads -> 4 MFMA each (2 key-sub x 2 q-sub) ----
                f32x4 s[2][2];
                #pragma unroll
                for (int a = 0; a < 2; ++a)
                    #pragma unroll
                    for (int b = 0; b < 2; ++b) { s[a][b][0]=0.f; s[a][b][1]=0.f; s[a][b][2]=0.f; s[a][b][3]=0.f; }
                __builtin_amdgcn_s_setprio(1);
                #pragma unroll
                for (int ks = 0; ks < 4; ++ks) {
                    const int e0 = (c*HD + 32*ks + 8*g) ^ ((c & 7) << 3);
                    bf16x8 ak0 = *(const bf16x8*)&bK[e0];
                    bf16x8 ak1 = *(const bf16x8*)&bK[e0 + 16*HD];
                    s[0][0] = __builtin_amdgcn_mfma_f32_16x16x32_bf16(ak0, qf[0][ks], s[0][0], 0, 0, 0);
                    s[0][1] = __builtin_amdgcn_mfma_f32_16x16x32_bf16(ak1, qf[0][ks], s[0][1], 0, 0, 0);
                    s[1][0] = __builtin_amdgcn_mfma_f32_16x16x32_bf16(ak0, qf[1][ks], s[1][0], 0, 0, 0);
                    s[1][1] = __builtin_amdgcn_mfma_f32_16x16x32_bf16(ak1, qf[1][ks], s[1][1], 0, 0, 0);
                }
                __builtin_amdgcn_s_setprio(0);

                // ---- causal mask (also fully masks an inactive subtile) ----
                if (k0 + 31 > qlo0) {
                    #pragma unroll
                    for (int sub = 0; sub < 2; ++sub) {
                        const int qg = qlo0 + 16*sub + c;
                        #pragma unroll
                        for (int r = 0; r < 4; ++r) {
                            if (k0 + 4*g + r > qg)      s[sub][0][r] = MASKV;
                            if (k0 + 16 + 4*g + r > qg) s[sub][1][r] = MASKV;
                        }
                    }
                }

                // ---- online softmax per subtile (exp2 domain, defer-max) ----
                bf16x8 pa[2];
                #pragma unroll
                for (int sub = 0; sub < 2; ++sub) {
                    float pmax = fmaxf(fmaxf(fmaxf(s[sub][0][0],s[sub][0][1]), fmaxf(s[sub][0][2],s[sub][0][3])),
                                       fmaxf(fmaxf(s[sub][1][0],s[sub][1][1]), fmaxf(s[sub][1][2],s[sub][1][3])));
                    pmax = fmaxf(pmax, __shfl_xor(pmax, 16, 64));
                    pmax = fmaxf(pmax, __shfl_xor(pmax, 32, 64));
                    if (!__all(pmax - mrow[sub] <= THRD)) {
                        const float mn = fmaxf(mrow[sub], pmax);
                        const float alpha = exp2f(mrow[sub] - mn);
                        mrow[sub] = mn;
                        f32x4 aq;
                        #pragma unroll
                        for (int r = 0; r < 4; ++r) aq[r] = __shfl(alpha, 20*g + r, 64);
                        #pragma unroll
                        for (int dt = 0; dt < 8; ++dt) oacc[sub][dt] *= aq;
                        lrow[sub] *= alpha;
                    }
                    float rs = 0.f;
                    #pragma unroll
                    for (int r = 0; r < 4; ++r) {
                        s[sub][0][r] = exp2f(s[sub][0][r] - mrow[sub]); rs += s[sub][0][r];
                        s[sub][1][r] = exp2f(s[sub][1][r] - mrow[sub]); rs += s[sub][1][r];
                    }
                    rs += __shfl_xor(rs, 16, 64);
                    rs += __shfl_xor(rs, 32, 64);
                    lrow[sub] += rs;

                    pa[sub][0]=(__bf16)s[sub][0][0]; pa[sub][1]=(__bf16)s[sub][0][1];
                    pa[sub][2]=(__bf16)s[sub][0][2]; pa[sub][3]=(__bf16)s[sub][0][3];
                    pa[sub][4]=(__bf16)s[sub][1][0]; pa[sub][5]=(__bf16)s[sub][1][1];
                    pa[sub][6]=(__bf16)s[sub][1][2]; pa[sub][7]=(__bf16)s[sub][1][3];
                }

                // ---- PV: 1 read -> 2 MFMA ----
                __builtin_amdgcn_s_setprio(1);
                #pragma unroll
                for (int dt = 0; dt < 8; ++dt) {
                    const int d = 16*dt + c;
                    const int e = d*KVB + ((8*g) ^ (((d >> 1) & 3) << 3));
                    bf16x8 bv = *(const bf16x8*)&bV[e];
                    oacc[0][dt] = __builtin_amdgcn_mfma_f32_16x16x32_bf16(pa[0], bv, oacc[0][dt], 0, 0, 0);
                    oacc[1][dt] = __builtin_amdgcn_mfma_f32_16x16x32_bf16(pa[1], bv, oacc[1][dt], 0, 0, 0);
                }
                __builtin_amdgcn_s_setprio(0);
            }
            buf ^= 1;
        }

        // ---- merge kv-halves (dump uses ALL 4 staging buffers: no prefetch live) ----
        __syncthreads();                 // all compute done, vmcnt drained
        float* dump = (float*)ldsraw;    // [128 q_local][128 d] fp32 = 64 KB
        if (grp == 1) {
            #pragma unroll
            for (int sub = 0; sub < 2; ++sub)
                if (lane < 16) {
                    ml[32*wg + 16*sub + c]       = mrow[sub];
                    ml[128 + 32*wg + 16*sub + c] = lrow[sub];
                }
            #pragma unroll
            for (int sub = 0; sub < 2; ++sub)
                #pragma unroll
                for (int dt = 0; dt < 8; ++dt)
                    #pragma unroll
                    for (int r = 0; r < 4; ++r)
                        dump[(32*wg + 16*sub + 4*g + r)*128 + 16*dt + c] = oacc[sub][dt][r];
        }
        __syncthreads();
        if (grp == 0) {
            #pragma unroll
            for (int sub = 0; sub < 2; ++sub) {
                const int ql = 32*wg + 16*sub;
                const float mB = ml[ql + c];
                const float lB = ml[128 + ql + c];
                const float mq = fmaxf(mrow[sub], mB);
                const float sA = exp2f(mrow[sub] - mq);
                const float sB = exp2f(mB - mq);
                const float inv = 1.0f / (lrow[sub]*sA + lB*sB);
                const float cA0 = sA * inv, cB0 = sB * inv;
                #pragma unroll
                for (int r = 0; r < 4; ++r) {
                    const float cA = __shfl(cA0, 20*g + r, 64);
                    const float cB = __shfl(cB0, 20*g + r, 64);
                    float* orow = O + (size_t)(q0 + ql + 4*g + r)*STR + h*HD;
                    #pragma unroll
                    for (int dt = 0; dt < 8; ++dt)
                        orow[16*dt + c] = oacc[sub][dt][r]*cA + dump[(ql + 4*g + r)*128 + 16*dt + c]*cB;
                }
            }
        }
        __syncthreads();                 // dump reads done before next phase's staging
    }
    #undef ISSUE
}

extern "C" void kernel_launch(void* const* d_in, const int* in_sizes, int n_in,
                              void* d_out, int out_size, void* d_ws, size_t ws_size,
                              hipStream_t stream) {
    const float* Q = (const float*)d_in[0];
    const float* K = (const float*)d_in[1];
    const float* V = (const float*)d_in[2];
    float* O = (float*)d_out;

    prep_kernel<<<dim3(NH * NT32), dim3(256), 0, stream>>>(K, V, (__bf16*)d_ws);
    fattn5_kernel<<<dim3(16 * NH), dim3(512), 0, stream>>>(Q, (const __bf16*)d_ws, O);
}